// Round 24
// baseline (154.627 us; speedup 1.0000x reference)
//
#include <hip/hip_runtime.h>
#include <hip/hip_cooperative_groups.h>
#include <cstdint>
#include <cstddef>

// CapsuleLayer dynamic routing, MI355X — R24.
// R23 fusion (transpose|route0|squash|route|squash|route|squash in ONE
// cooperative kernel, 6 grid.syncs) made ROBUST: host occupancy query gates
// the cooperative launch (R23's silent failure = co-residency rejection:
// absmax 0.879 == max|ref| -> out never written). If occ*256 < 512 blocks,
// fall back to the proven R20 7-kernel sequence (same device functions).
// ws: Wt 33,554,432 B | SP16 8,388,608 B | v0 262,144 B | v01 262,144 B.

namespace cg = cooperative_groups;

#define CN     2048
#define JN     32
#define UN     16
#define IN_    16
#define CPB    32
#define PAIRS  (CPB/2)       // 16
#define NCHUNK (CN/CPB)      // 64

typedef _Float16 f16;
typedef _Float16 f16x2 __attribute__((ext_vector_type(2)));
typedef _Float16 f16x4 __attribute__((ext_vector_type(4)));
typedef _Float16 f16x8 __attribute__((ext_vector_type(8)));
typedef __fp16   h16x2 __attribute__((ext_vector_type(2)));
typedef float    f32x4 __attribute__((ext_vector_type(4)));

static __device__ __forceinline__ f16x2 pkrtz(float a, float b) {
    h16x2 r = __builtin_amdgcn_cvt_pkrtz(a, b);
    return __builtin_bit_cast(f16x2, r);
}
static __device__ __forceinline__ float fdot2(f16x2 a, f16x2 b, float c) {
    return __builtin_amdgcn_fdot2(__builtin_bit_cast(h16x2, a),
                                  __builtin_bit_cast(h16x2, b), c, false);
}
struct P2 { f16x2 a, b; };
static __device__ __forceinline__ f16x4 join2(f16x2 a, f16x2 b) {
    P2 p{a, b};
    return __builtin_bit_cast(f16x4, p);
}
struct P4 { f16x4 a, b; };
static __device__ __forceinline__ f16x8 join4(f16x4 a, f16x4 b) {
    P4 p{a, b};
    return __builtin_bit_cast(f16x8, p);
}
static __device__ __forceinline__ f16x8 pk8(const float* w) {
    return join4(join2(pkrtz(w[0],w[1]), pkrtz(w[2],w[3])),
                 join2(pkrtz(w[4],w[5]), pkrtz(w[6],w[7])));
}
static __device__ __forceinline__ void lds_barrier() {
    asm volatile("s_waitcnt lgkmcnt(0)" ::: "memory");
    __builtin_amdgcn_s_barrier();
}

#define TJ 328
#define TI 20
#define T_SMEM 41936   // transpose tile bytes
#define R_SMEM 18432   // xs 16384 + psm 2048

// ---- transpose: W f32 [c][j][i][u] -> Wt f16 [c][j][u][i]; 4 c per 512-thr block ----
static __device__ void transpose_phase(const float* __restrict__ W,
                                       f16* __restrict__ Wt, char* smem, int bid)
{
    float* tile = (float*)smem;
    const int t = threadIdx.x;        // 0..511
    for (int cc = 0; cc < 4; ++cc) {
        const int c = bid*4 + cc;
#pragma unroll
        for (int h = 0; h < 4; ++h) {
            const int o = t*4 + h*2048;
            f32x4 v = *(const f32x4*)(W + (size_t)c*8192 + o);
            const int u0 = o & 15, i = (o >> 4) & 15, j = o >> 8;
            float* dst = tile + j*TJ + i*TI + u0;
            dst[0]=v[0]; dst[1]=v[1]; dst[2]=v[2]; dst[3]=v[3];
        }
        __syncthreads();
        {
            const int j = t >> 4, u = t & 15;
            float wv[16];
#pragma unroll
            for (int i = 0; i < 16; ++i) wv[i] = tile[j*TJ + i*TI + u];
            f16* dst = Wt + (size_t)c*8192 + j*256 + u*16;
            *(f16x8*)dst       = pk8(wv);
            *(f16x8*)(dst + 8) = pk8(wv + 8);
        }
        __syncthreads();
    }
}

// ---- route phase (R20 body; routed = uniform flag) ----
static __device__ void route_phase(const float* __restrict__ x,
                                   const f16* __restrict__ Wt,
                                   const float* __restrict__ v01g,
                                   f16* __restrict__ SP16,
                                   char* smem, bool routed, int bid)
{
    f16*   xs  = (f16*)smem;                  // 16384 B
    float* psm = (float*)(smem + 16384);      // 2048 B

    const int tid = threadIdx.x;
    const int l   = tid & 63;
    const int jg  = tid >> 6;
    const int g   = l >> 4;
    const int m15 = l & 15;

    const int xcd   = bid & 7;
    const int k     = bid >> 3;
    const int chunk = (k >> 3) * 8 + xcd;
    const int idx   = k & 7;
    const int bg    = idx >> 2;
    const int btl   = idx & 3;

    const int bl    = btl*16 + m15;
    const int bglob = bg*64 + bl;
    const int cbase = chunk * CPB;
    const int jbase = jg * 4;
    const int ccme  = g >> 1;

    {
        const int r = tid >> 5;
        const int s = tid & 31;
        const float* src = x + ((size_t)(bg*64 + btl*16 + r)*CN + cbase + s)*IN_;
        f32x4 a = *(const f32x4*)src;
        f32x4 b = *(const f32x4*)(src + 4);
        f32x4 c = *(const f32x4*)(src + 8);
        f32x4 d = *(const f32x4*)(src + 12);
        float lo8[8] = {a[0],a[1],a[2],a[3],b[0],b[1],b[2],b[3]};
        float hi8[8] = {c[0],c[1],c[2],c[3],d[0],d[1],d[2],d[3]};
        const int byte0 = r*1024 + s*32;
        const int sw    = (r & 7) << 4;
        *(f16x8*)((char*)xs + ((byte0     ) ^ sw)) = pk8(lo8);
        *(f16x8*)((char*)xs + ((byte0 + 16) ^ sw)) = pk8(hi8);
    }

    f16x2 vfr[4][2];
    if (routed) {
#pragma unroll
        for (int jj = 0; jj < 4; ++jj) {
            f32x4 vv = *(const f32x4*)(v01g + (size_t)bglob*512 + (jbase+jj)*16 + 4*g);
            vfr[jj][0] = pkrtz(vv[0], vv[1]);
            vfr[jj][1] = pkrtz(vv[2], vv[3]);
        }
    }

    f32x4 acc[4];
#pragma unroll
    for (int jj = 0; jj < 4; ++jj) acc[jj] = (f32x4){0.f,0.f,0.f,0.f};
    const f32x4 zero4 = {0.f,0.f,0.f,0.f};

    lds_barrier();

    const int xsw   = (m15 & 7) << 4;
    const int xbase = m15*1024 + ccme*32 + (g&1)*16;

    f16x8 wfr[2][4];
    f16x8 xq2[2];
    float lme2[2][4];

    auto LOADP = [&](int p) {
        const int s = p & 1;
        xq2[s] = *(const f16x8*)((const char*)xs + ((xbase + p*64) ^ xsw));
        const f16* wb = Wt + (size_t)(cbase + 2*p + ccme)*8192 + jbase*256
                        + m15*16 + (g&1)*8;
#pragma unroll
        for (int jj = 0; jj < 4; ++jj)
            wfr[s][jj] = *(const f16x8*)(wb + jj*256);
    };

    auto PHASEA = [&](int p) {
        const int s = p & 1;
        const f16x8 xq = xq2[s];
        f16x8 xz;
#pragma unroll
        for (int r = 0; r < 8; ++r) xz[r] = (f16)0.f;
        const f16x8 xb0 = (ccme == 0) ? xq : xz;
        const f16x8 xb1 = (ccme == 0) ? xz : xq;
        float summe = 0.f;
#pragma unroll
        for (int jj = 0; jj < 4; ++jj) {
            f32x4 uh0 = __builtin_amdgcn_mfma_f32_16x16x32_f16(wfr[s][jj], xb0, zero4, 0,0,0);
            float d0 = fdot2(pkrtz(uh0[0], uh0[1]), vfr[jj][0], 0.f);
            d0       = fdot2(pkrtz(uh0[2], uh0[3]), vfr[jj][1], d0);
            f32x4 uh1 = __builtin_amdgcn_mfma_f32_16x16x32_f16(wfr[s][jj], xb1, zero4, 0,0,0);
            float d1 = fdot2(pkrtz(uh1[0], uh1[1]), vfr[jj][0], 0.f);
            d1       = fdot2(pkrtz(uh1[2], uh1[3]), vfr[jj][1], d1);
            float t0 = d0 + __shfl_xor(d0, 16);
            float t1 = d1 + __shfl_xor(d1, 16);
            float sown = (ccme == 0) ? t0 : t1;
            float soth = (ccme == 0) ? t1 : t0;
            float dme  = sown + __shfl_xor(soth, 32);
            float e = __expf(dme);    // no max-sub: |logit| << 88
            summe += e;
            lme2[s][jj] = e;
        }
        if ((l & 31) < 16)
            psm[(s*2 + ccme)*128 + jg*16 + m15] = summe;
    };

    auto PHASEB = [&](int p, float myrden) {
        const int s = p & 1;
        const f16x8 xq = xq2[s];
#pragma unroll
        for (int jj = 0; jj < 4; ++jj) {
            f16x8 bx = xq;
            if (routed) {
                const f16 hsc = (f16)(lme2[s][jj] * myrden);
#pragma unroll
                for (int r = 0; r < 8; ++r) bx[r] = xq[r] * hsc;
            }
            acc[jj] = __builtin_amdgcn_mfma_f32_16x16x32_f16(wfr[s][jj], bx, acc[jj], 0,0,0);
        }
    };

    auto RDEN = [&](int p) -> float {
        const float* pp = &psm[((p & 1)*2 + ccme)*128 + m15];
        float d = 0.f;
#pragma unroll
        for (int q = 0; q < 8; ++q) d += pp[q*16];
        return 1.f / d;
    };

    LOADP(0);
    LOADP(1);
    if (routed) { PHASEA(0); lds_barrier(); }

#pragma unroll
    for (int p = 1; p < PAIRS; ++p) {
        float myrden = routed ? RDEN(p - 1) : 0.f;
        PHASEB(p - 1, myrden);
        if (p + 1 < PAIRS) LOADP(p + 1);
        if (routed) { PHASEA(p); lds_barrier(); }
    }
    {
        float myrden = routed ? RDEN(PAIRS - 1) : 0.f;
        PHASEB(PAIRS - 1, myrden);
    }

    f16* dst = SP16 + (((size_t)(bg*NCHUNK + chunk))*64 + bl)*512;
#pragma unroll
    for (int jj = 0; jj < 4; ++jj) {
        f32x4 a = acc[jj];
        *(f16x4*)(dst + (jbase+jj)*16 + 4*g) =
            join2(pkrtz(a[0], a[1]), pkrtz(a[2], a[3]));
    }
}

// ---- squash phase (bid 0..127 active; threads 0..255 do the work) ----
static __device__ void squash_phase(const f16* __restrict__ SP16,
                                    float* __restrict__ v0buf,
                                    float* __restrict__ v01buf,
                                    float* __restrict__ outp,
                                    int mode, char* smem, int bid)
{
    if (bid >= 128) return;
    float* sq   = (float*)smem;
    float* msqs = sq + 512;
    const int tid = threadIdx.x;
    const int b   = bid;
    const int bg  = b >> 6, blb = b & 63;

    float s0 = 0.f, s1 = 0.f;
    int j = 0, uh = 0;
    if (tid < 256) {
        j  = tid >> 3;
        uh = tid & 7;
        const f16* base = SP16 + ((size_t)(bg*NCHUNK)*64 + blb)*512 + j*16 + uh*2;
#pragma unroll 8
        for (int ch = 0; ch < NCHUNK; ++ch) {
            f16x2 v = *(const f16x2*)(base + (size_t)ch * 64 * 512);
            s0 += (float)v[0];
            s1 += (float)v[1];
        }
        if (mode == 0) { s0 *= (1.f/32.f); s1 *= (1.f/32.f); }
        sq[tid*2+0] = s0*s0;
        sq[tid*2+1] = s1*s1;
    }
    __syncthreads();
    if (tid < 16) {
        const int u = tid, uq = u >> 1, par = u & 1;
        float m = 0.f;
#pragma unroll
        for (int j2 = 0; j2 < 32; ++j2) m += sq[(j2*8 + uq)*2 + par];
        msqs[u] = m;
    }
    __syncthreads();
    if (tid < 256) {
        const size_t idx0 = (size_t)b*512 + j*16 + uh*2;
#pragma unroll
        for (int q = 0; q < 2; ++q) {
            const float s   = q ? s1 : s0;
            const float msq = msqs[uh*2 + q];
            const float mag = sqrtf(msq + 1e-8f);
            const float v   = (msq / (1.f + msq)) * (s / (mag + 1e-8f));
            const size_t idx = idx0 + q;
            if (mode == 0)      { v0buf[idx] = v; v01buf[idx] = v; }
            else if (mode == 1) { v01buf[idx] = v0buf[idx] + v; }
            else                { outp[idx] = v; }
        }
    }
}

// ---- fused cooperative kernel ----
__global__ __launch_bounds__(512)
void mega_kernel(const float* __restrict__ x, const float* __restrict__ W,
                 f16* __restrict__ Wt, f16* __restrict__ SP16,
                 float* __restrict__ v0, float* __restrict__ v01,
                 float* __restrict__ out)
{
    cg::grid_group grid = cg::this_grid();
    __shared__ alignas(16) char smem[T_SMEM];
    const int bid = blockIdx.x;

    transpose_phase(W, Wt, smem, bid);
    __threadfence(); grid.sync();

    route_phase(x, Wt, nullptr, SP16, smem, false, bid);
    __threadfence(); grid.sync();
    squash_phase(SP16, v0, v01, out, 0, smem, bid);
    __threadfence(); grid.sync();

    route_phase(x, Wt, v01, SP16, smem, true, bid);
    __threadfence(); grid.sync();
    squash_phase(SP16, v0, v01, out, 1, smem, bid);
    __threadfence(); grid.sync();

    route_phase(x, Wt, v01, SP16, smem, true, bid);
    __threadfence(); grid.sync();
    squash_phase(SP16, v0, v01, out, 2, smem, bid);
}

// ---- standalone fallback wrappers (= R20 path) ----
__global__ __launch_bounds__(512)
void transpose_k(const float* __restrict__ W, f16* __restrict__ Wt)
{
    __shared__ alignas(16) char smem[T_SMEM];
    transpose_phase(W, Wt, smem, blockIdx.x);
}
template<int ROUTED>
__global__ __launch_bounds__(512)
void route_k(const float* __restrict__ x, const f16* __restrict__ Wt,
             const float* __restrict__ v01g, f16* __restrict__ SP16)
{
    __shared__ alignas(16) char smem[R_SMEM];
    route_phase(x, Wt, v01g, SP16, smem, ROUTED != 0, blockIdx.x);
}
__global__ __launch_bounds__(512)
void squash_k(const f16* __restrict__ SP16, float* __restrict__ v0,
              float* __restrict__ v01, float* __restrict__ out, int mode)
{
    __shared__ alignas(16) char smem[2112 + 16];
    squash_phase(SP16, v0, v01, out, mode, smem, blockIdx.x);
}

extern "C" void kernel_launch(void* const* d_in, const int* in_sizes, int n_in,
                              void* d_out, int out_size, void* d_ws, size_t ws_size,
                              hipStream_t stream)
{
    const float* x = (const float*)d_in[0];
    const float* W = (const float*)d_in[1];

    f16*   Wt   = (f16*)d_ws;
    f16*   SP16 = (f16*)((char*)d_ws + (size_t)33554432);
    float* v0   = (float*)((char*)d_ws + (size_t)33554432 + 8388608);
    float* v01  = v0 + 65536;
    float* out  = (float*)d_out;

    // Deterministic host-side co-residency check (no stream ops, capture-safe).
    int occ = 0;
    hipError_t qe = hipOccupancyMaxActiveBlocksPerMultiprocessor(
        &occ, reinterpret_cast<const void*>(mega_kernel), 512, 0);
    const bool coop = (qe == hipSuccess) && (occ * 256 >= 512);

    if (coop) {
        void* args[] = { (void*)&x, (void*)&W, (void*)&Wt, (void*)&SP16,
                         (void*)&v0, (void*)&v01, (void*)&out };
        hipLaunchCooperativeKernel((void*)mega_kernel, dim3(512), dim3(512),
                                   args, 0, stream);
    } else {
        transpose_k<<<512, 512, 0, stream>>>(W, Wt);
        route_k<0> <<<512, 512, 0, stream>>>(x, Wt, nullptr, SP16);
        squash_k   <<<128, 512, 0, stream>>>(SP16, v0, v01, out, 0);
        route_k<1> <<<512, 512, 0, stream>>>(x, Wt, v01, SP16);
        squash_k   <<<128, 512, 0, stream>>>(SP16, v0, v01, out, 1);
        route_k<1> <<<512, 512, 0, stream>>>(x, Wt, v01, SP16);
        squash_k   <<<128, 512, 0, stream>>>(SP16, v0, v01, out, 2);
    }
}

// Round 25
// 116.239 us; speedup vs baseline: 1.3302x; 1.3302x over previous
//
#include <hip/hip_runtime.h>
#include <cstdint>
#include <cstddef>

// CapsuleLayer dynamic routing, MI355X — R25 = R20 verbatim (best: 115.9 us).
// Fusion experiments (R23/R24) abandoned: cooperative mega-kernel can't
// co-reside (512 blocks) and the shared-device-function fallback perturbed
// codegen (57 us routed vs 30). This restores the exact proven source.
// Structure: CPB=32, 512-thr route blocks (8 waves, j-span 4), distance-2
// register ring for Wt fragments (direct-global, no W staging), LDS-staged
// swizzled x, ping-pong psm with lgkmcnt-only barriers, chunk->XCD swizzle,
// f16 SP intermediate, 256-thr vectorized squash, LDS-tiled W transpose.
// ws: Wt 33,554,432 B | SP16 8,388,608 B | v0 262,144 B | v01 262,144 B.

#define CN     2048
#define JN     32
#define UN     16
#define IN_    16
#define CPB    32
#define PAIRS  (CPB/2)       // 16
#define NCHUNK (CN/CPB)      // 64
#define NBG    2             // b-groups of 64

typedef _Float16 f16;
typedef _Float16 f16x2 __attribute__((ext_vector_type(2)));
typedef _Float16 f16x4 __attribute__((ext_vector_type(4)));
typedef _Float16 f16x8 __attribute__((ext_vector_type(8)));
typedef __fp16   h16x2 __attribute__((ext_vector_type(2)));
typedef float    f32x4 __attribute__((ext_vector_type(4)));

static __device__ __forceinline__ f16x2 pkrtz(float a, float b) {
    h16x2 r = __builtin_amdgcn_cvt_pkrtz(a, b);
    return __builtin_bit_cast(f16x2, r);
}
static __device__ __forceinline__ float fdot2(f16x2 a, f16x2 b, float c) {
    return __builtin_amdgcn_fdot2(__builtin_bit_cast(h16x2, a),
                                  __builtin_bit_cast(h16x2, b), c, false);
}
struct P2 { f16x2 a, b; };
static __device__ __forceinline__ f16x4 join2(f16x2 a, f16x2 b) {
    P2 p{a, b};
    return __builtin_bit_cast(f16x4, p);
}
struct P4 { f16x4 a, b; };
static __device__ __forceinline__ f16x8 join4(f16x4 a, f16x4 b) {
    P4 p{a, b};
    return __builtin_bit_cast(f16x8, p);
}
static __device__ __forceinline__ f16x8 pk8(const float* w) {
    return join4(join2(pkrtz(w[0],w[1]), pkrtz(w[2],w[3])),
                 join2(pkrtz(w[4],w[5]), pkrtz(w[6],w[7])));
}
// LDS-only barrier: psm/xs visibility needs lgkmcnt, NOT vmcnt -> prefetch
// global loads stay outstanding across the barrier.
static __device__ __forceinline__ void lds_barrier() {
    asm volatile("s_waitcnt lgkmcnt(0)" ::: "memory");
    __builtin_amdgcn_s_barrier();
}

// W f32 [c][j][i][u] -> Wt f16 [c][j][u][i] via padded LDS tile.
#define TJ 328
#define TI 20
__global__ __launch_bounds__(256)
void transpose_W(const float* __restrict__ W, f16* __restrict__ Wt)
{
    __shared__ float tile[31*TJ + 15*TI + 16];
    const int c = blockIdx.x;
    const int t = threadIdx.x;
#pragma unroll
    for (int h = 0; h < 8; ++h) {
        const int o = t*4 + h*1024;
        f32x4 v = *(const f32x4*)(W + (size_t)c*8192 + o);
        const int u0 = o & 15, i = (o >> 4) & 15, j = o >> 8;
        float* dst = tile + j*TJ + i*TI + u0;
        dst[0]=v[0]; dst[1]=v[1]; dst[2]=v[2]; dst[3]=v[3];
    }
    __syncthreads();
#pragma unroll
    for (int h = 0; h < 2; ++h) {
        const int s = t + h*256;
        const int j = s >> 4, u = s & 15;
        float wv[16];
#pragma unroll
        for (int i = 0; i < 16; ++i) wv[i] = tile[j*TJ + i*TI + u];
        f16* dst = Wt + (size_t)c*8192 + j*256 + u*16;
        *(f16x8*)dst       = pk8(wv);
        *(f16x8*)(dst + 8) = pk8(wv + 8);
    }
}

template<int ROUTED>
__global__ __launch_bounds__(512)
void route_kernel(const float* __restrict__ x, const f16* __restrict__ Wt,
                  const float* __restrict__ v01g, f16* __restrict__ SP16)
{
    __shared__ f16   xs[8192];        // [r 16][c 32][i 16] f16, XOR-swizzled
    __shared__ float psm[2][2*8*16];  // ping-pong [cc 2][jg 8][b 16]

    const int tid = threadIdx.x;
    const int l   = tid & 63;
    const int jg  = tid >> 6;
    const int g   = l >> 4;
    const int m15 = l & 15;

    const int bid   = blockIdx.x;
    const int xcd   = bid & 7;
    const int k     = bid >> 3;
    const int chunk = (k >> 3) * 8 + xcd;
    const int idx   = k & 7;
    const int bg    = idx >> 2;
    const int btl   = idx & 3;

    const int bl    = btl*16 + m15;
    const int bglob = bg*64 + bl;
    const int cbase = chunk * CPB;
    const int jbase = jg * 4;
    const int ccme  = g >> 1;

    // stage x slice (16b x 32c x 16i) -> LDS f16, swizzled
    {
        const int r = tid >> 5;
        const int s = tid & 31;
        const float* src = x + ((size_t)(bg*64 + btl*16 + r)*CN + cbase + s)*IN_;
        f32x4 a = *(const f32x4*)src;
        f32x4 b = *(const f32x4*)(src + 4);
        f32x4 c = *(const f32x4*)(src + 8);
        f32x4 d = *(const f32x4*)(src + 12);
        float lo8[8] = {a[0],a[1],a[2],a[3],b[0],b[1],b[2],b[3]};
        float hi8[8] = {c[0],c[1],c[2],c[3],d[0],d[1],d[2],d[3]};
        const int byte0 = r*1024 + s*32;
        const int sw    = (r & 7) << 4;
        *(f16x8*)((char*)xs + ((byte0     ) ^ sw)) = pk8(lo8);
        *(f16x8*)((char*)xs + ((byte0 + 16) ^ sw)) = pk8(hi8);
    }

    f16x2 vfr[4][2];
    if (ROUTED) {
#pragma unroll
        for (int jj = 0; jj < 4; ++jj) {
            f32x4 vv = *(const f32x4*)(v01g + (size_t)bglob*512 + (jbase+jj)*16 + 4*g);
            vfr[jj][0] = pkrtz(vv[0], vv[1]);
            vfr[jj][1] = pkrtz(vv[2], vv[3]);
        }
    }

    f32x4 acc[4];
#pragma unroll
    for (int jj = 0; jj < 4; ++jj) acc[jj] = (f32x4){0.f,0.f,0.f,0.f};
    const f32x4 zero4 = {0.f,0.f,0.f,0.f};

    lds_barrier();                    // xs ready

    const int xsw   = (m15 & 7) << 4;
    const int xbase = m15*1024 + ccme*32 + (g&1)*16;

    f16x8 wfr[2][4];
    f16x8 xq2[2];
    float lme2[2][4];

    auto LOADP = [&](int p) {
        const int s = p & 1;
        xq2[s] = *(const f16x8*)((const char*)xs + ((xbase + p*64) ^ xsw));
        const f16* wb = Wt + (size_t)(cbase + 2*p + ccme)*8192 + jbase*256
                        + m15*16 + (g&1)*8;
#pragma unroll
        for (int jj = 0; jj < 4; ++jj)
            wfr[s][jj] = *(const f16x8*)(wb + jj*256);
    };

    auto PHASEA = [&](int p) {
        const int s = p & 1;
        const f16x8 xq = xq2[s];
        f16x8 xz;
#pragma unroll
        for (int r = 0; r < 8; ++r) xz[r] = (f16)0.f;
        const f16x8 xb0 = (ccme == 0) ? xq : xz;
        const f16x8 xb1 = (ccme == 0) ? xz : xq;
        float summe = 0.f;
#pragma unroll
        for (int jj = 0; jj < 4; ++jj) {
            f32x4 uh0 = __builtin_amdgcn_mfma_f32_16x16x32_f16(wfr[s][jj], xb0, zero4, 0,0,0);
            float d0 = fdot2(pkrtz(uh0[0], uh0[1]), vfr[jj][0], 0.f);
            d0       = fdot2(pkrtz(uh0[2], uh0[3]), vfr[jj][1], d0);
            f32x4 uh1 = __builtin_amdgcn_mfma_f32_16x16x32_f16(wfr[s][jj], xb1, zero4, 0,0,0);
            float d1 = fdot2(pkrtz(uh1[0], uh1[1]), vfr[jj][0], 0.f);
            d1       = fdot2(pkrtz(uh1[2], uh1[3]), vfr[jj][1], d1);
            float t0 = d0 + __shfl_xor(d0, 16);
            float t1 = d1 + __shfl_xor(d1, 16);
            float sown = (ccme == 0) ? t0 : t1;
            float soth = (ccme == 0) ? t1 : t0;
            float dme  = sown + __shfl_xor(soth, 32);
            float e = __expf(dme);    // no max-sub: |logit| << 88
            summe += e;
            lme2[s][jj] = e;
        }
        if ((l & 31) < 16)
            psm[s][(ccme*8 + jg)*16 + m15] = summe;
    };

    auto PHASEB = [&](int p, float myrden) {
        const int s = p & 1;
        const f16x8 xq = xq2[s];
#pragma unroll
        for (int jj = 0; jj < 4; ++jj) {
            f16x8 bx = xq;
            if (ROUTED) {
                const f16 hsc = (f16)(lme2[s][jj] * myrden);
#pragma unroll
                for (int r = 0; r < 8; ++r) bx[r] = xq[r] * hsc;   // v_pk_mul_f16
            }
            acc[jj] = __builtin_amdgcn_mfma_f32_16x16x32_f16(wfr[s][jj], bx, acc[jj], 0,0,0);
        }
    };

    auto RDEN = [&](int p) -> float {
        const float* pp = &psm[p & 1][ccme*128 + m15];
        float d = 0.f;
#pragma unroll
        for (int q = 0; q < 8; ++q) d += pp[q*16];
        return 1.f / d;
    };

    LOADP(0);
    LOADP(1);
    if (ROUTED) { PHASEA(0); lds_barrier(); }

#pragma unroll
    for (int p = 1; p < PAIRS; ++p) {
        float myrden = 0.f;
        if (ROUTED) myrden = RDEN(p - 1);
        PHASEB(p - 1, myrden);
        if (p + 1 < PAIRS) LOADP(p + 1);
        if (ROUTED) { PHASEA(p); lds_barrier(); }
    }
    {
        float myrden = 0.f;
        if (ROUTED) myrden = RDEN(PAIRS - 1);
        PHASEB(PAIRS - 1, myrden);
    }

    // partial s -> f16: SP16[((bg*64+chunk)*64 + bl)*512 + j*16 + 4g]
    f16* dst = SP16 + (((size_t)(bg*NCHUNK + chunk))*64 + bl)*512;
#pragma unroll
    for (int jj = 0; jj < 4; ++jj) {
        f32x4 a = acc[jj];
        *(f16x4*)(dst + (jbase+jj)*16 + 4*g) =
            join2(pkrtz(a[0], a[1]), pkrtz(a[2], a[3]));
    }
}

// Reduce 64 chunk-partials (f16), squash over J. grid 128 (b), block 256.
__global__ __launch_bounds__(256)
void squash_kernel(const f16* __restrict__ SP16, float* __restrict__ v0buf,
                   float* __restrict__ v01buf, float* __restrict__ outp, int mode)
{
    __shared__ float sq[256*2];
    __shared__ float msqs[16];
    const int tid = threadIdx.x;
    const int j   = tid >> 3;
    const int uh  = tid & 7;
    const int b   = blockIdx.x;
    const int bg  = b >> 6, blb = b & 63;

    const f16* base = SP16 + ((size_t)(bg*NCHUNK)*64 + blb)*512 + j*16 + uh*2;
    float s0 = 0.f, s1 = 0.f;
#pragma unroll 8
    for (int ch = 0; ch < NCHUNK; ++ch) {
        f16x2 v = *(const f16x2*)(base + (size_t)ch * 64 * 512);
        s0 += (float)v[0];
        s1 += (float)v[1];
    }
    if (mode == 0) { s0 *= (1.f/32.f); s1 *= (1.f/32.f); }

    sq[tid*2+0] = s0*s0;
    sq[tid*2+1] = s1*s1;
    __syncthreads();
    if (tid < 16) {
        const int u = tid, uq = u >> 1, par = u & 1;
        float m = 0.f;
#pragma unroll
        for (int j2 = 0; j2 < 32; ++j2) m += sq[(j2*8 + uq)*2 + par];
        msqs[u] = m;
    }
    __syncthreads();

    const size_t idx0 = (size_t)b*512 + j*16 + uh*2;
#pragma unroll
    for (int q = 0; q < 2; ++q) {
        const float s   = q ? s1 : s0;
        const float msq = msqs[uh*2 + q];
        const float mag = sqrtf(msq + 1e-8f);
        const float v   = (msq / (1.f + msq)) * (s / (mag + 1e-8f));
        const size_t idx = idx0 + q;
        if (mode == 0)      { v0buf[idx] = v; v01buf[idx] = v; }
        else if (mode == 1) { v01buf[idx] = v0buf[idx] + v; }   // b2 uses v0+v1
        else                { outp[idx] = v; }
    }
}

extern "C" void kernel_launch(void* const* d_in, const int* in_sizes, int n_in,
                              void* d_out, int out_size, void* d_ws, size_t ws_size,
                              hipStream_t stream)
{
    const float* x = (const float*)d_in[0];
    const float* W = (const float*)d_in[1];

    // ws: Wt (32 MiB f16) | SP16 (8 MiB f16) | v0 | v01
    f16*   Wt   = (f16*)d_ws;
    f16*   SP16 = (f16*)((char*)d_ws + (size_t)33554432);
    float* v0   = (float*)((char*)d_ws + (size_t)33554432 + 8388608);
    float* v01  = v0 + 65536;
    float* out  = (float*)d_out;

    transpose_W<<<2048, 256, 0, stream>>>(W, Wt);

    dim3 grid(512), blk(512);
    route_kernel<0><<<grid, blk, 0, stream>>>(x, Wt, nullptr, SP16);
    squash_kernel  <<<128, 256, 0, stream>>>(SP16, v0, v01, out, 0);
    route_kernel<1><<<grid, blk, 0, stream>>>(x, Wt, v01, SP16);
    squash_kernel  <<<128, 256, 0, stream>>>(SP16, v0, v01, out, 1);
    route_kernel<1><<<grid, blk, 0, stream>>>(x, Wt, v01, SP16);
    squash_kernel  <<<128, 256, 0, stream>>>(SP16, v0, v01, out, 2);
}